// Round 4
// baseline (373.412 us; speedup 1.0000x reference)
//
#include <hip/hip_runtime.h>

typedef __attribute__((ext_vector_type(8))) short short8;
typedef __attribute__((ext_vector_type(4))) float floatx4;

__device__ __forceinline__ unsigned short f2bf(float f) {
  union { float f; unsigned u; } v; v.f = f;
  unsigned r = v.u + 0x7fffu + ((v.u >> 16) & 1u);   // RNE
  return (unsigned short)(r >> 16);
}
// round-half-up pack of two floats to bf16x2
__device__ __forceinline__ unsigned pk2(float lo, float hi) {
  union { float f; unsigned u; } a, b; a.f = lo; b.f = hi;
  return ((a.u + 0x8000u) >> 16) | ((b.u + 0x8000u) & 0xffff0000u);
}
__device__ __forceinline__ float bf2f(unsigned short h) {
  union { unsigned u; float f; } v; v.u = ((unsigned)h) << 16; return v.f;
}
__device__ __forceinline__ float fexp2(float x) {
#if __has_builtin(__builtin_amdgcn_exp2f)
  return __builtin_amdgcn_exp2f(x);
#else
  return exp2f(x);
#endif
}

#define MFMA16(a, b, c) __builtin_amdgcn_mfma_f32_16x16x32_bf16((a), (b), (c), 0, 0, 0)

// Q scale: 1/sqrt(64) * log2(e), so softmax is exp2 of raw scores.
#define QSCALE 0.18033688011112042f

// ---------------------------------------------------------------------------
// Kernel 0: Wt[n][k] bf16, n in [0,192) over {Wq|Wk|Wv}, k in [0,768)
// ---------------------------------------------------------------------------
__global__ void wt_kernel(const float* __restrict__ Wq, const float* __restrict__ Wk,
                          const float* __restrict__ Wv, unsigned short* __restrict__ Wt) {
  int i = blockIdx.x * 256 + threadIdx.x;
  if (i >= 192 * 768) return;
  int n = i / 768, k = i - n * 768;
  const float* W = (n < 64) ? Wq : (n < 128) ? Wk : Wv;
  Wt[i] = f2bf(W[k * 64 + (n & 63)]);
}

// ---------------------------------------------------------------------------
// Kernel 1: QKV GEMM v4 — barrier-free. 64 rows/block, wave = 4 m-tiles x
// 3 n-tiles. A-frags read+cvt directly from x (global), B-frags directly
// from L2-resident Wt. No LDS in the K-loop; single barrier only for the
// V^T epilogue transpose.
// ---------------------------------------------------------------------------
__global__ __launch_bounds__(256, 2) void qkv_kernel(const float* __restrict__ x,
                                                     const unsigned short* __restrict__ Wt,
                                                     unsigned short* __restrict__ Qb,
                                                     unsigned short* __restrict__ Kb,
                                                     unsigned short* __restrict__ Vt) {
  __shared__ __align__(16) unsigned short VL[64 * 72];   // V^T transpose staging

  int tid = threadIdx.x;
  int wv = tid >> 6, l15 = tid & 15, quad = (tid & 63) >> 4;
  int r0 = blockIdx.x * 64;

  floatx4 acc[4][3];
#pragma unroll
  for (int mt = 0; mt < 4; ++mt)
#pragma unroll
    for (int nt = 0; nt < 3; ++nt) acc[mt][nt] = (floatx4){0.f, 0.f, 0.f, 0.f};

  const float* xb = x + (size_t)r0 * 768;
  const unsigned short* wb = Wt + (size_t)(wv * 48 + l15) * 768;

#pragma unroll 1
  for (int it = 0; it < 12; ++it) {
    int k0 = it * 64;
#pragma unroll
    for (int s = 0; s < 2; ++s) {
      int ko = k0 + s * 32 + quad * 8;
      short8 af[4];
#pragma unroll
      for (int mt = 0; mt < 4; ++mt) {
        const float* ap = xb + (size_t)(mt * 16 + l15) * 768 + ko;
        float4 g0 = *(const float4*)ap;
        float4 g1 = *(const float4*)(ap + 4);
        unsigned u[4] = {pk2(g0.x, g0.y), pk2(g0.z, g0.w), pk2(g1.x, g1.y), pk2(g1.z, g1.w)};
        af[mt] = *(short8*)u;
      }
      short8 bf[3];
#pragma unroll
      for (int nt = 0; nt < 3; ++nt)
        bf[nt] = *(const short8*)(wb + (size_t)nt * 16 * 768 + ko);
#pragma unroll
      for (int mt = 0; mt < 4; ++mt)
#pragma unroll
        for (int nt = 0; nt < 3; ++nt)
          acc[mt][nt] = MFMA16(af[mt], bf[nt], acc[mt][nt]);
    }
  }

  // ---- epilogue: Q/K direct, V through LDS transpose ----
#pragma unroll
  for (int mt = 0; mt < 4; ++mt)
#pragma unroll
    for (int nt = 0; nt < 3; ++nt)
#pragma unroll
      for (int r = 0; r < 4; ++r) {
        int grow = r0 + mt * 16 + quad * 4 + r;
        int col = (wv * 3 + nt) * 16 + l15;
        float val = acc[mt][nt][r];
        if (col < 64) {
          Qb[(size_t)grow * 64 + col] = f2bf(val * QSCALE);
        } else if (col < 128) {
          Kb[(size_t)grow * 64 + (col - 64)] = f2bf(val);
        } else {
          VL[(col - 128) * 72 + (mt * 16 + quad * 4 + r)] = f2bf(val);
        }
      }
  __syncthreads();
  int bb = r0 >> 13, s0 = r0 & 8191;
#pragma unroll
  for (int c = 0; c < 2; ++c) {
    int chunk = c * 256 + tid;           // 512 chunks = 64 hd x 8 groups
    int hd = chunk >> 3, sg = chunk & 7;
    short8 vv = *(short8*)&VL[hd * 72 + sg * 8];
    *(short8*)(Vt + ((size_t)(bb * 64 + hd)) * 8192 + s0 + sg * 8) = vv;
  }
}

// ---------------------------------------------------------------------------
// Kernel 2: causal flash attention v4 — ZERO barriers. Wave = 32q x K-range,
// K-split x4 (4096 independent waves, 16/CU). K A-frags and V B-frags loaded
// directly from global (L2-resident); only the wave-private P transpose uses
// LDS. S^T = K*Q^T formulation; no-shift softmax via exp2 (log2e folded in Q).
// ---------------------------------------------------------------------------
__global__ __launch_bounds__(256, 3) void attn_kernel(const unsigned short* __restrict__ Qb,
                                                      const unsigned short* __restrict__ Kb,
                                                      const unsigned short* __restrict__ Vt,
                                                      unsigned short* __restrict__ Ob,
                                                      float* __restrict__ Lw) {
  __shared__ __align__(16) unsigned short Ps[4][32 * 64];   // per-wave P, 16 KB total

  int tid = threadIdx.x;
  int wv = tid >> 6, ln = tid & 63, l15 = ln & 15, quad = ln >> 4;
  int sw = l15 & 7;
  int u = blockIdx.x * 4 + wv;           // wave-unit 0..4095
  int qi = 255 - (u >> 4);               // 32-query tile, biggest extent first
  int sub = u & 15, b = sub & 3, sp = sub >> 2;
  int q0 = qi * 32;
  int nk = (q0 >> 6) + 1;                // 64-key tiles covering [0, q0+32)
  int g0 = (nk * sp) >> 2, g1 = (nk * (sp + 1)) >> 2;
  size_t bbase = (size_t)b * 8192;

  // Q B-fragments, in regs for the whole kernel
  short8 qf[2][2];
#pragma unroll
  for (int t = 0; t < 2; ++t)
#pragma unroll
    for (int s = 0; s < 2; ++s)
      qf[t][s] = *(const short8*)(Qb + (bbase + q0 + t * 16 + l15) * 64 + s * 32 + quad * 8);

  floatx4 oa[2][4];
#pragma unroll
  for (int t = 0; t < 2; ++t)
#pragma unroll
    for (int nt = 0; nt < 4; ++nt) oa[t][nt] = (floatx4){0.f, 0.f, 0.f, 0.f};
  float lp[2] = {0.f, 0.f};
  unsigned short* Pw = &Ps[wv][0];
  const unsigned short* Kbb = Kb + bbase * 64;
  const unsigned short* Vbb = Vt + (size_t)b * 64 * 8192;

#pragma unroll 1
  for (int g = g0; g < g1; ++g) {
    int kb = g << 6;
    bool diag = (g == nk - 1);           // only split sp=3 ever masks

    // ---- S^T = K * Q^T : K A-frags direct from global (2KB/instr coalesced) ----
    floatx4 sc[4][2];
#pragma unroll
    for (int mt = 0; mt < 4; ++mt) {
      const unsigned short* kr = Kbb + (size_t)(kb + mt * 16 + l15) * 64;
      short8 k0 = *(const short8*)(kr + quad * 8);
      short8 k1 = *(const short8*)(kr + 32 + quad * 8);
#pragma unroll
      for (int t = 0; t < 2; ++t) {
        floatx4 z = (floatx4){0.f, 0.f, 0.f, 0.f};
        z = MFMA16(k0, qf[t][0], z);
        sc[mt][t] = MFMA16(k1, qf[t][1], z);
      }
    }

    // ---- exp2 (no shift, no mul), causal mask on diag, P write (b64) ----
#pragma unroll
    for (int t = 0; t < 2; ++t) {
      int qg = q0 + t * 16 + l15;
#pragma unroll
      for (int mt = 0; mt < 4; ++mt) {
        float p[4];
#pragma unroll
        for (int r = 0; r < 4; ++r) {
          float e = fexp2(sc[mt][t][r]);
          if (diag) {
            int kg = kb + mt * 16 + quad * 4 + r;
            if (kg > qg) e = 0.f;
          }
          p[r] = e;
          lp[t] += e;
        }
        int row = t * 16 + l15;
        int sgw = (mt * 4 + quad) ^ (sw << 1);
        unsigned long long dd =
            (unsigned long long)pk2(p[0], p[1]) | ((unsigned long long)pk2(p[2], p[3]) << 32);
        *(unsigned long long*)&Pw[row * 64 + sgw * 4] = dd;
      }
    }

    // ---- O += P V : P A-frags from wave-private LDS, V B-frags from global ----
#pragma unroll
    for (int s = 0; s < 2; ++s) {
      short8 pA[2];
#pragma unroll
      for (int t = 0; t < 2; ++t)
        pA[t] = *(short8*)&Pw[(t * 16 + l15) * 64 + (((s * 8 + quad * 2) ^ (sw << 1)) << 2)];
#pragma unroll
      for (int nt = 0; nt < 4; ++nt) {
        short8 vf = *(const short8*)(Vbb + (size_t)(nt * 16 + l15) * 8192 + kb + s * 32 + quad * 8);
#pragma unroll
        for (int t = 0; t < 2; ++t) oa[t][nt] = MFMA16(pA[t], vf, oa[t][nt]);
      }
    }
  }

  // ---- epilogue: partial l + unnormalized bf16 O ----
  int hb = sp * 4 + b;
#pragma unroll
  for (int t = 0; t < 2; ++t) {
    float l = lp[t];
    l += __shfl_xor(l, 16);
    l += __shfl_xor(l, 32);
    if (quad == t) Lw[(size_t)hb * 8192 + q0 + t * 16 + l15] = l;
  }
#pragma unroll
  for (int t = 0; t < 2; ++t)
#pragma unroll
    for (int nt = 0; nt < 4; ++nt)
#pragma unroll
      for (int r = 0; r < 4; ++r) {
        int ql = q0 + t * 16 + quad * 4 + r;
        Ob[((size_t)hb * 8192 + ql) * 64 + nt * 16 + l15] = f2bf(oa[t][nt][r]);
      }
}

// ---------------------------------------------------------------------------
// Kernel 3: combine 4 K-split partials: out = (sum O_s) / (sum l_s)
// ---------------------------------------------------------------------------
__global__ __launch_bounds__(256) void combine_kernel(const unsigned short* __restrict__ Ob,
                                                      const float* __restrict__ Lw,
                                                      float* __restrict__ out) {
  int idx = (blockIdx.x * 256 + threadIdx.x) * 4;   // 4 hd per thread
  int r = idx >> 6, hd = idx & 63;
  float inv = 1.f / (Lw[r] + Lw[32768 + r] + Lw[65536 + r] + Lw[98304 + r]);
  float o0 = 0.f, o1 = 0.f, o2 = 0.f, o3 = 0.f;
#pragma unroll
  for (int sp = 0; sp < 4; ++sp) {
    uint2 a = *(const uint2*)(Ob + (size_t)sp * 32768 * 64 + (size_t)r * 64 + hd);
    o0 += bf2f((unsigned short)(a.x & 0xffff));
    o1 += bf2f((unsigned short)(a.x >> 16));
    o2 += bf2f((unsigned short)(a.y & 0xffff));
    o3 += bf2f((unsigned short)(a.y >> 16));
  }
  float4 o = {o0 * inv, o1 * inv, o2 * inv, o3 * inv};
  *(float4*)(out + idx) = o;
}

// ---------------------------------------------------------------------------
extern "C" void kernel_launch(void* const* d_in, const int* in_sizes, int n_in,
                              void* d_out, int out_size, void* d_ws, size_t ws_size,
                              hipStream_t stream) {
  const float* x  = (const float*)d_in[0];
  const float* Wq = (const float*)d_in[1];
  const float* Wk = (const float*)d_in[2];
  const float* Wv = (const float*)d_in[3];
  float* out = (float*)d_out;

  const size_t M = (size_t)4 * 8192;                 // 32768 rows
  unsigned short* Qb = (unsigned short*)d_ws;        // [32768][64] bf16 (Q*scale*log2e)
  unsigned short* Kb = Qb + M * 64;                  // [32768][64] bf16
  unsigned short* Vt = Kb + M * 64;                  // [4][64][8192] bf16 (V^T)
  unsigned short* Wt = Vt + M * 64;                  // [192][768] bf16 (W^T)
  unsigned short* Ob = Wt + (size_t)192 * 768;       // [4][4][8192][64] bf16 partial O
  float*          Lw = (float*)(Ob + (size_t)4 * M * 64);  // [4][4][8192] partial l

  wt_kernel<<<576, 256, 0, stream>>>(Wq, Wk, Wv, Wt);
  qkv_kernel<<<512, 256, 0, stream>>>(x, Wt, Qb, Kb, Vt);
  attn_kernel<<<1024, 256, 0, stream>>>(Qb, Kb, Vt, Ob, Lw);
  combine_kernel<<<2048, 256, 0, stream>>>(Ob, Lw, out);
}

// Round 5
// 227.238 us; speedup vs baseline: 1.6433x; 1.6433x over previous
//
#include <hip/hip_runtime.h>

typedef __attribute__((ext_vector_type(8))) short short8;
typedef __attribute__((ext_vector_type(4))) float floatx4;

__device__ __forceinline__ unsigned short f2bf(float f) {
  union { float f; unsigned u; } v; v.f = f;
  unsigned r = v.u + 0x7fffu + ((v.u >> 16) & 1u);   // RNE
  return (unsigned short)(r >> 16);
}
// round-half-up pack of two floats to bf16x2
__device__ __forceinline__ unsigned pk2(float lo, float hi) {
  union { float f; unsigned u; } a, b; a.f = lo; b.f = hi;
  return ((a.u + 0x8000u) >> 16) | ((b.u + 0x8000u) & 0xffff0000u);
}
__device__ __forceinline__ float bf2f(unsigned short h) {
  union { unsigned u; float f; } v; v.u = ((unsigned)h) << 16; return v.f;
}
__device__ __forceinline__ float fexp2(float x) {
#if __has_builtin(__builtin_amdgcn_exp2f)
  return __builtin_amdgcn_exp2f(x);
#else
  return exp2f(x);
#endif
}
__device__ __forceinline__ void gl2lds16(const void* g, void* l) {
  __builtin_amdgcn_global_load_lds(
      (const __attribute__((address_space(1))) void*)g,
      (__attribute__((address_space(3))) void*)l, 16, 0, 0);
}

#define MFMA16(a, b, c) __builtin_amdgcn_mfma_f32_16x16x32_bf16((a), (b), (c), 0, 0, 0)

// Q scale: 1/sqrt(64) * log2(e) -> softmax is a bare exp2 of raw scores.
#define QSCALE 0.18033688011112042f

// ---------------------------------------------------------------------------
// Kernel 0: Wt[n][k] bf16, n in [0,192) over {Wq|Wk|Wv}, k in [0,768)
// ---------------------------------------------------------------------------
__global__ void wt_kernel(const float* __restrict__ Wq, const float* __restrict__ Wk,
                          const float* __restrict__ Wv, unsigned short* __restrict__ Wt) {
  int i = blockIdx.x * 256 + threadIdx.x;
  if (i >= 192 * 768) return;
  int n = i / 768, k = i - n * 768;
  const float* W = (n < 64) ? Wq : (n < 128) ? Wk : Wv;
  Wt[i] = f2bf(W[k * 64 + (n & 63)]);
}

// ---------------------------------------------------------------------------
// Kernel 1: QKV GEMM (R3-proven). 64 rows/block, N=192, K-step 64. Single-
// buffered Ws (reg-held fragments), dbuf As, packed cvt, LDS-transposed
// coalesced V^T epilogue.
// ---------------------------------------------------------------------------
__global__ __launch_bounds__(256, 3) void qkv_kernel(const float* __restrict__ x,
                                                     const unsigned short* __restrict__ Wt,
                                                     unsigned short* __restrict__ Qb,
                                                     unsigned short* __restrict__ Kb,
                                                     unsigned short* __restrict__ Vt) {
  __shared__ __align__(16) unsigned short As[2][64 * 72];
  __shared__ __align__(16) unsigned short Ws[192 * 64];   // XOR-swizzled groups

  int tid = threadIdx.x;
  int wv = tid >> 6, l15 = tid & 15, quad = (tid & 63) >> 4;
  int sw = l15 & 7;
  int r0 = blockIdx.x * 64;

  floatx4 acc[4][3];
#pragma unroll
  for (int mt = 0; mt < 4; ++mt)
#pragma unroll
    for (int nt = 0; nt < 3; ++nt) acc[mt][nt] = (floatx4){0.f, 0.f, 0.f, 0.f};

  int arow = tid >> 2, acg = tid & 3;
  const float* xs = x + (size_t)(r0 + arow) * 768 + acg * 16;
  int asoff = arow * 72 + acg * 16;

  // ---- prologue ----
  {
    float4 f0 = *(const float4*)(xs);
    float4 f1 = *(const float4*)(xs + 4);
    float4 f2 = *(const float4*)(xs + 8);
    float4 f3 = *(const float4*)(xs + 12);
    unsigned u[8] = {pk2(f0.x, f0.y), pk2(f0.z, f0.w), pk2(f1.x, f1.y), pk2(f1.z, f1.w),
                     pk2(f2.x, f2.y), pk2(f2.z, f2.w), pk2(f3.x, f3.y), pk2(f3.z, f3.w)};
    *(short8*)&As[0][asoff] = *(short8*)&u[0];
    *(short8*)&As[0][asoff + 8] = *(short8*)&u[4];
#pragma unroll
    for (int c = 0; c < 6; ++c) {
      int slot = c * 256 + tid;
      int r = slot >> 3, g = slot & 7, gs = g ^ (r & 7);
      gl2lds16(Wt + r * 768 + gs * 8, &Ws[slot * 8]);
    }
  }
  __syncthreads();

  for (int it = 0; it < 12; ++it) {
    int cur = it & 1, nxt = cur ^ 1, k1 = (it + 1) * 64;
    short8 af[4][2], bf[3][2];
#pragma unroll
    for (int mt = 0; mt < 4; ++mt)
#pragma unroll
      for (int s = 0; s < 2; ++s)
        af[mt][s] = *(short8*)&As[cur][(mt * 16 + l15) * 72 + s * 32 + quad * 8];
#pragma unroll
    for (int nt = 0; nt < 3; ++nt)
#pragma unroll
      for (int s = 0; s < 2; ++s)
        bf[nt][s] = *(short8*)&Ws[((wv * 3 + nt) * 16 + l15) * 64 +
                                  (((s * 4 + quad) ^ sw) << 3)];
    float4 f0, f1, f2, f3;
    if (it < 11) {
      f0 = *(const float4*)(xs + k1);
      f1 = *(const float4*)(xs + k1 + 4);
      f2 = *(const float4*)(xs + k1 + 8);
      f3 = *(const float4*)(xs + k1 + 12);
    }
    __syncthreads();   // all Ws/As reads done
    if (it < 11) {
#pragma unroll
      for (int c = 0; c < 6; ++c) {
        int slot = c * 256 + tid;
        int r = slot >> 3, g = slot & 7, gs = g ^ (r & 7);
        gl2lds16(Wt + r * 768 + k1 + gs * 8, &Ws[slot * 8]);
      }
      unsigned u[8] = {pk2(f0.x, f0.y), pk2(f0.z, f0.w), pk2(f1.x, f1.y), pk2(f1.z, f1.w),
                       pk2(f2.x, f2.y), pk2(f2.z, f2.w), pk2(f3.x, f3.y), pk2(f3.z, f3.w)};
      *(short8*)&As[nxt][asoff] = *(short8*)&u[0];
      *(short8*)&As[nxt][asoff + 8] = *(short8*)&u[4];
    }
#pragma unroll
    for (int s = 0; s < 2; ++s)
#pragma unroll
      for (int mt = 0; mt < 4; ++mt)
#pragma unroll
        for (int nt = 0; nt < 3; ++nt)
          acc[mt][nt] = MFMA16(af[mt][s], bf[nt][s], acc[mt][nt]);
    __syncthreads();
  }

  // ---- epilogue: Q/K direct, V through LDS transpose ----
  unsigned short* VL = &As[0][0];
#pragma unroll
  for (int mt = 0; mt < 4; ++mt)
#pragma unroll
    for (int nt = 0; nt < 3; ++nt)
#pragma unroll
      for (int r = 0; r < 4; ++r) {
        int grow = r0 + mt * 16 + quad * 4 + r;
        int col = (wv * 3 + nt) * 16 + l15;
        float val = acc[mt][nt][r];
        if (col < 64) {
          Qb[(size_t)grow * 64 + col] = f2bf(val * QSCALE);
        } else if (col < 128) {
          Kb[(size_t)grow * 64 + (col - 64)] = f2bf(val);
        } else {
          VL[(col - 128) * 72 + (mt * 16 + quad * 4 + r)] = f2bf(val);
        }
      }
  __syncthreads();
  int bb = r0 >> 13, s0 = r0 & 8191;
#pragma unroll
  for (int c = 0; c < 2; ++c) {
    int chunk = c * 256 + tid;
    int hd = chunk >> 3, sg = chunk & 7;
    short8 vv = *(short8*)&VL[hd * 72 + sg * 8];
    *(short8*)(Vt + ((size_t)(bb * 64 + hd)) * 8192 + s0 + sg * 8) = vv;
  }
}

// ---------------------------------------------------------------------------
// Kernel 2: causal flash attention v5. 256-thr blocks = 4 waves x 32q = 128q,
// shared K/V staging (gl2lds, K dbuf), K-split x4, biggest-first, wave-level
// skip of fully-masked tiles. S^T = K*Q^T; no-shift exp2 softmax; wave-private
// P transpose in LDS. LDS 40KB -> 4 blocks/CU.
// ---------------------------------------------------------------------------
__global__ __launch_bounds__(256, 4) void attn_kernel(const unsigned short* __restrict__ Qb,
                                                      const unsigned short* __restrict__ Kb,
                                                      const unsigned short* __restrict__ Vt,
                                                      unsigned short* __restrict__ Ob,
                                                      float* __restrict__ Lw) {
  __shared__ __align__(16) unsigned short Ks[2][64 * 64];  // [key][d] swizzled
  __shared__ __align__(16) unsigned short Vts[64 * 64];    // [hd][key] swizzled
  __shared__ __align__(16) unsigned short Ps[4][32 * 64];  // per-wave P swizzled

  int tid = threadIdx.x;
  int wv = tid >> 6, ln = tid & 63, l15 = ln & 15, quad = ln >> 4;
  int sw = l15 & 7;
  int bid = blockIdx.x;
  int qt = 63 - (bid >> 4);               // 128q tile, biggest extent first
  int sub = bid & 15, sp = sub >> 2, b = sub & 3;
  int nk = 2 * (qt + 1);                  // 64-key tiles covering block's queries
  int g0 = (nk * sp) >> 2, g1 = (nk * (sp + 1)) >> 2;
  int qw = qt * 128 + wv * 32;            // wave's q base (within batch)
  size_t bbase = (size_t)b * 8192;
  const unsigned short* Kbb = Kb + bbase * 64;
  const unsigned short* Vbb = Vt + (size_t)b * 64 * 8192;

  short8 qf[2][2];
#pragma unroll
  for (int t = 0; t < 2; ++t)
#pragma unroll
    for (int s = 0; s < 2; ++s)
      qf[t][s] = *(const short8*)(Qb + (bbase + qw + t * 16 + l15) * 64 + s * 32 + quad * 8);

  floatx4 oa[2][4];
#pragma unroll
  for (int t = 0; t < 2; ++t)
#pragma unroll
    for (int nt = 0; nt < 4; ++nt) oa[t][nt] = (floatx4){0.f, 0.f, 0.f, 0.f};
  float lp[2] = {0.f, 0.f};
  unsigned short* Pw = &Ps[wv][0];

  if (g0 < g1) {
    // prologue: stage K(g0)
#pragma unroll
    for (int c = 0; c < 2; ++c) {
      int slot = c * 256 + tid;
      int r = slot >> 3, g = slot & 7, gs = g ^ (r & 7);
      gl2lds16(Kbb + (size_t)(g0 * 64 + r) * 64 + gs * 8, &Ks[0][slot * 8]);
    }
    __syncthreads();

    for (int g = g0; g < g1; ++g) {
      int cur = (g - g0) & 1, kb = g << 6;
      // stage V(g) (drains at barrier1, hidden behind QK+exp)
#pragma unroll
      for (int c = 0; c < 2; ++c) {
        int slot = c * 256 + tid;
        int r = slot >> 3, gg = slot & 7, gs = gg ^ (r & 7);
        gl2lds16(Vbb + (size_t)r * 8192 + kb + gs * 8, &Vts[slot * 8]);
      }
      if (g + 1 < g1) {   // async next-K into other buffer
#pragma unroll
        for (int c = 0; c < 2; ++c) {
          int slot = c * 256 + tid;
          int r = slot >> 3, gg = slot & 7, gs = gg ^ (r & 7);
          gl2lds16(Kbb + (size_t)(kb + 64 + r) * 64 + gs * 8, &Ks[cur ^ 1][slot * 8]);
        }
      }

      bool active = kb < qw + 32;          // wave has unmasked work in this tile
      bool edge = kb + 64 > qw;            // tile straddles the causal diagonal
      if (active) {
        // ---- S^T = K * Q^T ----
        floatx4 sc[4][2];
#pragma unroll
        for (int mt = 0; mt < 4; ++mt) {
          int krow = mt * 16 + l15;
          short8 k0 = *(short8*)&Ks[cur][krow * 64 + ((quad ^ sw) << 3)];
          short8 k1 = *(short8*)&Ks[cur][krow * 64 + (((4 + quad) ^ sw) << 3)];
#pragma unroll
          for (int t = 0; t < 2; ++t) {
            floatx4 z = (floatx4){0.f, 0.f, 0.f, 0.f};
            z = MFMA16(k0, qf[t][0], z);
            sc[mt][t] = MFMA16(k1, qf[t][1], z);
          }
        }
        // ---- exp2 (no shift), causal mask on edge tiles, P write (b64) ----
#pragma unroll
        for (int t = 0; t < 2; ++t) {
          int qg = qw + t * 16 + l15;
#pragma unroll
          for (int mt = 0; mt < 4; ++mt) {
            float p[4];
#pragma unroll
            for (int r = 0; r < 4; ++r) {
              float e = fexp2(sc[mt][t][r]);
              if (edge) {
                int kg = kb + mt * 16 + quad * 4 + r;
                if (kg > qg) e = 0.f;
              }
              p[r] = e;
              lp[t] += e;
            }
            int row = t * 16 + l15;
            int sgw = (mt * 4 + quad) ^ (sw << 1);
            unsigned long long dd =
                (unsigned long long)pk2(p[0], p[1]) | ((unsigned long long)pk2(p[2], p[3]) << 32);
            *(unsigned long long*)&Pw[row * 64 + sgw * 4] = dd;
          }
        }
      }
      __syncthreads();   // V(g) + K(g+1) landed; all Ks[cur] reads done

      if (active) {
        // ---- O += P V ----
#pragma unroll
        for (int s = 0; s < 2; ++s) {
          short8 pA[2];
#pragma unroll
          for (int t = 0; t < 2; ++t)
            pA[t] = *(short8*)&Pw[(t * 16 + l15) * 64 + (((s * 8 + quad * 2) ^ (sw << 1)) << 2)];
#pragma unroll
          for (int nt = 0; nt < 4; ++nt) {
            short8 vf = *(short8*)&Vts[(nt * 16 + l15) * 64 + (((s * 4 + quad) ^ sw) << 3)];
#pragma unroll
            for (int t = 0; t < 2; ++t) oa[t][nt] = MFMA16(pA[t], vf, oa[t][nt]);
          }
        }
      }
      __syncthreads();   // protect Vts/Ks before next stage
    }
  }

  // ---- epilogue (unconditional: empty splits write zeros) ----
  int hb = sp * 4 + b;
#pragma unroll
  for (int t = 0; t < 2; ++t) {
    float l = lp[t];
    l += __shfl_xor(l, 16);
    l += __shfl_xor(l, 32);
    if (quad == t) Lw[(size_t)hb * 8192 + qw + t * 16 + l15] = l;
  }
#pragma unroll
  for (int t = 0; t < 2; ++t)
#pragma unroll
    for (int nt = 0; nt < 4; ++nt)
#pragma unroll
      for (int r = 0; r < 4; ++r) {
        int ql = qw + t * 16 + quad * 4 + r;
        Ob[((size_t)hb * 8192 + ql) * 64 + nt * 16 + l15] = f2bf(oa[t][nt][r]);
      }
}

// ---------------------------------------------------------------------------
// Kernel 3: combine 4 K-split partials: out = (sum O_s) / (sum l_s)
// ---------------------------------------------------------------------------
__global__ __launch_bounds__(256) void combine_kernel(const unsigned short* __restrict__ Ob,
                                                      const float* __restrict__ Lw,
                                                      float* __restrict__ out) {
  int idx = (blockIdx.x * 256 + threadIdx.x) * 4;   // 4 hd per thread
  int r = idx >> 6, hd = idx & 63;
  float inv = 1.f / (Lw[r] + Lw[32768 + r] + Lw[65536 + r] + Lw[98304 + r]);
  float o0 = 0.f, o1 = 0.f, o2 = 0.f, o3 = 0.f;
#pragma unroll
  for (int sp = 0; sp < 4; ++sp) {
    uint2 a = *(const uint2*)(Ob + (size_t)sp * 32768 * 64 + (size_t)r * 64 + hd);
    o0 += bf2f((unsigned short)(a.x & 0xffff));
    o1 += bf2f((unsigned short)(a.x >> 16));
    o2 += bf2f((unsigned short)(a.y & 0xffff));
    o3 += bf2f((unsigned short)(a.y >> 16));
  }
  float4 o = {o0 * inv, o1 * inv, o2 * inv, o3 * inv};
  *(float4*)(out + idx) = o;
}

// ---------------------------------------------------------------------------
extern "C" void kernel_launch(void* const* d_in, const int* in_sizes, int n_in,
                              void* d_out, int out_size, void* d_ws, size_t ws_size,
                              hipStream_t stream) {
  const float* x  = (const float*)d_in[0];
  const float* Wq = (const float*)d_in[1];
  const float* Wk = (const float*)d_in[2];
  const float* Wv = (const float*)d_in[3];
  float* out = (float*)d_out;

  const size_t M = (size_t)4 * 8192;                 // 32768 rows
  unsigned short* Qb = (unsigned short*)d_ws;        // [32768][64] bf16 (Q*scale*log2e)
  unsigned short* Kb = Qb + M * 64;                  // [32768][64] bf16
  unsigned short* Vt = Kb + M * 64;                  // [4][64][8192] bf16 (V^T)
  unsigned short* Wt = Vt + M * 64;                  // [192][768] bf16 (W^T)
  unsigned short* Ob = Wt + (size_t)192 * 768;       // [4][4][8192][64] bf16 partial O
  float*          Lw = (float*)(Ob + (size_t)4 * M * 64);  // [4][4][8192] partial l

  wt_kernel<<<576, 256, 0, stream>>>(Wq, Wk, Wv, Wt);
  qkv_kernel<<<512, 256, 0, stream>>>(x, Wt, Qb, Kb, Vt);
  attn_kernel<<<1024, 256, 0, stream>>>(Qb, Kb, Vt, Ob, Lw);
  combine_kernel<<<2048, 256, 0, stream>>>(Ob, Lw, out);
}